// Round 3
// baseline (381.362 us; speedup 1.0000x reference)
//
#include <hip/hip_runtime.h>
#include <hip/hip_bf16.h>

#define T_STEPS 256
#define BATCH   2048
#define INSZ    65
#define HID     64
#define ROWS    4        // batch rows per block -> 512 blocks = 2 blocks/CU
#define S       272      // LDS row stride (shorts): x0[64] x1[64] h0[64] h1[64] pad[16]
                         // S/2 = 136 words == 8 mod 32 -> 2-way max on b128 reads (free)
#define XLOFF   (4*S)    // x[:,64] slots: 2 parities x 4 rows (bf16)
#define OUTSZ   7
#define NTHREADS 256

typedef __attribute__((ext_vector_type(8))) short bf16x8;  // 8 bf16 in 4 VGPRs
typedef __attribute__((ext_vector_type(4))) float f32x4;

__device__ __forceinline__ short f2bf(float f) {
    union { float f; unsigned u; } v; v.f = f;
    unsigned r = (v.u + 0x7FFFu + ((v.u >> 16) & 1u)) >> 16;  // RNE
    return (short)r;
}
__device__ __forceinline__ float bf2f(short s) {
    union { unsigned u; float f; } v;
    v.u = ((unsigned)(unsigned short)s) << 16;
    return v.f;
}
__device__ __forceinline__ float sigm(float x) {
    return 1.0f / (1.0f + __expf(-x));
}
__device__ __forceinline__ float tanh_f(float x) {
    return 1.0f - 2.0f / (__expf(2.0f * x) + 1.0f);  // saturates at +-1
}
// select element `quad` of a f32x4 (3 v_cndmask after mask setup)
__device__ __forceinline__ float sel4(f32x4 v, int quad) {
    const float a = (quad & 1) ? v[1] : v[0];
    const float b = (quad & 1) ? v[3] : v[2];
    return (quad & 2) ? b : a;
}

__global__ __launch_bounds__(NTHREADS, 2)   // <=256 VGPR, 2 blocks/CU
void lstm_fused(const float* __restrict__ x,    const float* __restrict__ W_ih,
                const float* __restrict__ W_hh, const float* __restrict__ b_ih,
                const float* __restrict__ b_hh, const float* __restrict__ fc_W,
                const float* __restrict__ fc_b, float* __restrict__ out)
{
    __shared__ __align__(16) short Abuf[XLOFF + 8];

    const int tid  = threadIdx.x;
    const int w    = tid >> 6;        // wave 0..3 = N-tile (cols 16w..16w+15)
    const int lane = tid & 63;
    const int quad = lane >> 4;       // also: batch row this lane activates
    const int col  = lane & 15;
    const int b0   = blockIdx.x * ROWS;

    // zero LDS once: h0 buffer = h(-1) = 0, pads = 0
    for (int i = tid; i < XLOFF + 8; i += NTHREADS) Abuf[i] = 0;

    // ---- W fragments: wave w owns ALL 4 gates of its N-tile ----
    // B-operand layout: n = lane&15, k = quad*8 + j.  K: 0..63 = x, 64..127 = h.
    bf16x8 wfrag[4][4];
    float  wl[4], bias[4];
    #pragma unroll
    for (int gt = 0; gt < 4; ++gt) {
        const int n = gt * 64 + w * 16 + col;   // gate-major weight row
        #pragma unroll
        for (int kc = 0; kc < 2; ++kc) {        // x part
            bf16x8 f;
            #pragma unroll
            for (int j = 0; j < 8; ++j)
                f[j] = f2bf(W_ih[n * INSZ + kc * 32 + quad * 8 + j]);
            wfrag[gt][kc] = f;
        }
        #pragma unroll
        for (int kc = 2; kc < 4; ++kc) {        // h part
            bf16x8 f;
            #pragma unroll
            for (int j = 0; j < 8; ++j)
                f[j] = f2bf(W_hh[n * HID + (kc - 2) * 32 + quad * 8 + j]);
            wfrag[gt][kc] = f;
        }
        wl[gt]   = W_ih[n * INSZ + 64];         // rank-1 fixup column (k=64)
        bias[gt] = b_ih[n] + b_hh[n];
    }

    // ---- x staging: thread (w, lane) owns x[b0+w][t][lane]; 2-deep prefetch ----
    const float* xq = x + (size_t)(b0 + w) * T_STEPS * INSZ + lane;
    float xr  = xq[0];            // x_t   (t=0)
    float xr2 = xq[INSZ];         // x_{t+1}
    xq += 2 * INSZ;
    const float* xe = x + (size_t)(b0 + tid) * T_STEPS * INSZ + 64;  // x[:,64]
    float xer = 0.f, xer2 = 0.f;
    if (tid < 4) { xer = xe[0]; xer2 = xe[INSZ]; }
    xe += 2 * INSZ;

    float c = 0.0f;               // cell state: row=quad, col=w*16+col
    __syncthreads();

    for (int t = 0; t < T_STEPS; ++t) {
        const int par = t & 1;
        // stage x_t into parity buffer (disjoint from buffers any laggard reads)
        Abuf[w * S + par * 64 + lane] = f2bf(xr);
        if (tid < 4) Abuf[XLOFF + par * 4 + tid] = f2bf(xer);
        xr = xr2; xer = xer2;
        xr2 = xq[0];
        if (tid < 4) xer2 = xe[0];
        if (t < T_STEPS - 3) { xq += INSZ; xe += INSZ; }
        __syncthreads();   // the ONLY barrier per step

        // A fragments, replicated rows: m_phys -> batch row m_phys&3 (LDS broadcast)
        const int abase = (col & 3) * S + quad * 8;
        const int xoff  = par * 64;
        const int hoff  = 128 + par * 64;
        const bf16x8 a0 = *(const bf16x8*)&Abuf[abase + xoff];
        const bf16x8 a1 = *(const bf16x8*)&Abuf[abase + xoff + 32];
        const bf16x8 a2 = *(const bf16x8*)&Abuf[abase + hoff];
        const bf16x8 a3 = *(const bf16x8*)&Abuf[abase + hoff + 32];
        const float xlf = bf2f(Abuf[XLOFF + par * 4 + quad]);   // x_t[quad][64]

        f32x4 acc[4];
        #pragma unroll
        for (int gt = 0; gt < 4; ++gt) {
            f32x4 a = {bias[gt], bias[gt], bias[gt], bias[gt]};
            a = __builtin_amdgcn_mfma_f32_16x16x32_bf16(a0, wfrag[gt][0], a, 0, 0, 0);
            a = __builtin_amdgcn_mfma_f32_16x16x32_bf16(a1, wfrag[gt][1], a, 0, 0, 0);
            a = __builtin_amdgcn_mfma_f32_16x16x32_bf16(a2, wfrag[gt][2], a, 0, 0, 0);
            a = __builtin_amdgcn_mfma_f32_16x16x32_bf16(a3, wfrag[gt][3], a, 0, 0, 0);
            acc[gt] = a;
        }

        // reg r = batch row r in every quad; quad q activates row q
        const float gi = sel4(acc[0], quad) + wl[0] * xlf;
        const float gf = sel4(acc[1], quad) + wl[1] * xlf;
        const float gg = sel4(acc[2], quad) + wl[2] * xlf;
        const float go = sel4(acc[3], quad) + wl[3] * xlf;
        const float ig = sigm(gi);
        const float fg = sigm(gf);
        const float g  = tanh_f(gg);
        const float og = sigm(go);
        c = fg * c + ig * g;
        const float h = og * tanh_f(c);
        // h_t -> OTHER parity buffer (read next step); 64 lanes -> 32 banks once
        Abuf[quad * S + 128 + (par ^ 1) * 64 + w * 16 + col] = f2bf(h);
    }
    __syncthreads();

    // ---- FC(64->7) + sigmoid; final h is in hbuf parity 0 (t=255 wrote 128..191)
    if (tid < ROWS * OUTSZ) {
        const int m = tid & 3;
        const int o = tid >> 2;
        float s = fc_b[o];
        #pragma unroll
        for (int k = 0; k < HID; ++k)
            s += bf2f(Abuf[m * S + 128 + k]) * fc_W[o * HID + k];
        out[(size_t)(b0 + m) * OUTSZ + o] = sigm(s);
    }
}

extern "C" void kernel_launch(void* const* d_in, const int* in_sizes, int n_in,
                              void* d_out, int out_size, void* d_ws, size_t ws_size,
                              hipStream_t stream) {
    const float* x    = (const float*)d_in[0];
    const float* W_ih = (const float*)d_in[1];
    const float* W_hh = (const float*)d_in[2];
    const float* b_ih = (const float*)d_in[3];
    const float* b_hh = (const float*)d_in[4];
    const float* fc_W = (const float*)d_in[5];
    const float* fc_b = (const float*)d_in[6];
    float* out = (float*)d_out;

    dim3 grid(BATCH / ROWS);    // 512 blocks -> 2 per CU
    dim3 block(NTHREADS);       // 4 waves
    hipLaunchKernelGGL(lstm_fused, grid, block, 0, stream,
                       x, W_ih, W_hh, b_ih, b_hh, fc_W, fc_b, out);
}

// Round 4
// 335.807 us; speedup vs baseline: 1.1357x; 1.1357x over previous
//
#include <hip/hip_runtime.h>
#include <hip/hip_bf16.h>

#define T_STEPS 256
#define BATCH   2048
#define INSZ    65
#define HID     64
#define ROWS    4        // batch rows per block -> 512 blocks = 2 blocks/CU
#define S       272      // LDS row stride (shorts): x0[64] x1[64] h0[64] h1[64] pad
#define OUTSZ   7
#define NTHREADS 256

typedef __attribute__((ext_vector_type(8))) short bf16x8;  // 8 bf16 in 4 VGPRs
typedef __attribute__((ext_vector_type(4))) float f32x4;

__device__ __forceinline__ short f2bf(float f) {
    union { float f; unsigned u; } v; v.f = f;
    unsigned r = (v.u + 0x7FFFu + ((v.u >> 16) & 1u)) >> 16;  // RNE
    return (short)r;
}
__device__ __forceinline__ float bf2f(short s) {
    union { unsigned u; float f; } v;
    v.u = ((unsigned)(unsigned short)s) << 16;
    return v.f;
}
__device__ __forceinline__ float sigm(float x) {
    return 1.0f / (1.0f + __expf(-x));
}
__device__ __forceinline__ float tanh_f(float x) {
    return 1.0f - 2.0f / (__expf(2.0f * x) + 1.0f);  // saturates at +-1
}
__device__ __forceinline__ float sel4(f32x4 v, int quad) {
    const float a = (quad & 1) ? v[1] : v[0];
    const float b = (quad & 1) ? v[3] : v[2];
    return (quad & 2) ? b : a;
}

__global__ __launch_bounds__(NTHREADS, 2)
void lstm_fused(const float* __restrict__ x,    const float* __restrict__ W_ih,
                const float* __restrict__ W_hh, const float* __restrict__ b_ih,
                const float* __restrict__ b_hh, const float* __restrict__ fc_W,
                const float* __restrict__ fc_b, float* __restrict__ out)
{
    __shared__ __align__(16) short Abuf[ROWS * S];

    const int tid  = threadIdx.x;
    const int w    = tid >> 6;        // wave 0..3 = N-tile (cols 16w..16w+15)
    const int lane = tid & 63;
    const int quad = lane >> 4;       // batch row this lane activates
    const int col  = lane & 15;
    const int b0   = blockIdx.x * ROWS;

    for (int i = tid; i < ROWS * S; i += NTHREADS) Abuf[i] = 0;  // h(-1)=0, pads=0

    // ---- W fragments: wave w owns ALL 4 gates of its N-tile ----
    // B layout: n = lane&15, k = quad*8+j.  K: 0..63 = x[0..63], 64..127 = h.
    bf16x8 wfrag[4][4];
    float  wl[4];
    f32x4  bias4[4];                  // MFMA C-operand init (loop-invariant)
    #pragma unroll
    for (int gt = 0; gt < 4; ++gt) {
        const int n = gt * 64 + w * 16 + col;
        #pragma unroll
        for (int kc = 0; kc < 2; ++kc) {
            bf16x8 f;
            #pragma unroll
            for (int j = 0; j < 8; ++j)
                f[j] = f2bf(W_ih[n * INSZ + kc * 32 + quad * 8 + j]);
            wfrag[gt][kc] = f;
        }
        #pragma unroll
        for (int kc = 2; kc < 4; ++kc) {
            bf16x8 f;
            #pragma unroll
            for (int j = 0; j < 8; ++j)
                f[j] = f2bf(W_hh[n * HID + (kc - 2) * 32 + quad * 8 + j]);
            wfrag[gt][kc] = f;
        }
        wl[gt] = W_ih[n * INSZ + 64];                 // k=64 rank-1 fixup
        const float bv = b_ih[n] + b_hh[n];
        bias4[gt] = (f32x4){bv, bv, bv, bv};
    }

    // ---- global-load pipeline (2 steps deep; consumed 1.5-2 bodies later
    //      so the barrier's vmcnt(0) drain finds them already complete) ----
    // staging: thread (w,lane) owns x[b0+w][t][lane]  (k 0..63; exact 256 elems)
    const float* xsp = x + (size_t)(b0 + w) * T_STEPS * INSZ + lane;
    // activation fixup: lane reads x[b0+quad][t][64]
    const float* xep = x + (size_t)(b0 + quad) * T_STEPS * INSZ + 64;

    const float xs0 = xsp[0];          // x_0 (staged pre-loop)
    float xr0 = xsp[INSZ];             // x_1 (staged at end of body 0)
    float xlA = xep[0];                // x64 for even bodies (t)
    float xlB = xep[INSZ];             // x64 for odd bodies (t+1)
    xsp += 2 * INSZ; xep += 2 * INSZ;  // -> t = 2

    float c = 0.0f;
    __syncthreads();                   // zero-init visible
    Abuf[w * S + lane] = f2bf(xs0);    // stage x_0 into parity 0
    __syncthreads();

    const int abase = (col & 3) * S + quad * 8;

    for (int t = 0; t < T_STEPS; t += 2) {
        // ================= body t (parity 0) =================
        {
            const float xr1  = xsp[0];      // x_{t+2}  (issue early, use late)
            const float xlA2 = xep[0];      // x64_{t+2}

            const bf16x8 a0 = *(const bf16x8*)&Abuf[abase +   0];  // x lo
            const bf16x8 a1 = *(const bf16x8*)&Abuf[abase +  32];  // x hi
            const bf16x8 a2 = *(const bf16x8*)&Abuf[abase + 128];  // h lo
            const bf16x8 a3 = *(const bf16x8*)&Abuf[abase + 160];  // h hi

            f32x4 acc[4];
            #pragma unroll
            for (int gt = 0; gt < 4; ++gt) {
                f32x4 a = __builtin_amdgcn_mfma_f32_16x16x32_bf16(a0, wfrag[gt][0], bias4[gt], 0, 0, 0);
                a = __builtin_amdgcn_mfma_f32_16x16x32_bf16(a1, wfrag[gt][1], a, 0, 0, 0);
                a = __builtin_amdgcn_mfma_f32_16x16x32_bf16(a2, wfrag[gt][2], a, 0, 0, 0);
                a = __builtin_amdgcn_mfma_f32_16x16x32_bf16(a3, wfrag[gt][3], a, 0, 0, 0);
                acc[gt] = a;
            }

            const float ig = sigm(__builtin_fmaf(wl[0], xlA, sel4(acc[0], quad)));
            const float fg = sigm(__builtin_fmaf(wl[1], xlA, sel4(acc[1], quad)));
            const float g  = tanh_f(__builtin_fmaf(wl[2], xlA, sel4(acc[2], quad)));
            const float og = sigm(__builtin_fmaf(wl[3], xlA, sel4(acc[3], quad)));
            c = fg * c + ig * g;
            const float h = og * tanh_f(c);

            Abuf[quad * S + 192 + w * 16 + col] = f2bf(h);   // h_t -> parity 1
            Abuf[w * S + 64 + lane] = f2bf(xr0);             // x_{t+1} -> parity 1
            xr0 = xr1; xlA = xlA2;
            if (t < 253) { xsp += INSZ; xep += INSZ; }       // next fetch: t+3
        }
        __syncthreads();

        // ================= body t+1 (parity 1) =================
        {
            const float xr1  = xsp[0];      // x_{t+3}
            const float xlB2 = xep[0];      // x64_{t+3}

            const bf16x8 a0 = *(const bf16x8*)&Abuf[abase +  64];
            const bf16x8 a1 = *(const bf16x8*)&Abuf[abase +  96];
            const bf16x8 a2 = *(const bf16x8*)&Abuf[abase + 192];
            const bf16x8 a3 = *(const bf16x8*)&Abuf[abase + 224];

            f32x4 acc[4];
            #pragma unroll
            for (int gt = 0; gt < 4; ++gt) {
                f32x4 a = __builtin_amdgcn_mfma_f32_16x16x32_bf16(a0, wfrag[gt][0], bias4[gt], 0, 0, 0);
                a = __builtin_amdgcn_mfma_f32_16x16x32_bf16(a1, wfrag[gt][1], a, 0, 0, 0);
                a = __builtin_amdgcn_mfma_f32_16x16x32_bf16(a2, wfrag[gt][2], a, 0, 0, 0);
                a = __builtin_amdgcn_mfma_f32_16x16x32_bf16(a3, wfrag[gt][3], a, 0, 0, 0);
                acc[gt] = a;
            }

            const float ig = sigm(__builtin_fmaf(wl[0], xlB, sel4(acc[0], quad)));
            const float fg = sigm(__builtin_fmaf(wl[1], xlB, sel4(acc[1], quad)));
            const float g  = tanh_f(__builtin_fmaf(wl[2], xlB, sel4(acc[2], quad)));
            const float og = sigm(__builtin_fmaf(wl[3], xlB, sel4(acc[3], quad)));
            c = fg * c + ig * g;
            const float h = og * tanh_f(c);

            Abuf[quad * S + 128 + w * 16 + col] = f2bf(h);   // h_{t+1} -> parity 0
            Abuf[w * S + lane] = f2bf(xr0);                  // x_{t+2} -> parity 0
            xr0 = xr1; xlB = xlB2;
            if (t < 252) { xsp += INSZ; xep += INSZ; }       // next fetch: t+4
        }
        __syncthreads();
    }

    // ---- FC(64->7) + sigmoid; final h (t=255) is in parity-0 h region (128..191)
    if (tid < ROWS * OUTSZ) {
        const int m = tid & 3;
        const int o = tid >> 2;
        float s = fc_b[o];
        #pragma unroll
        for (int k = 0; k < HID; ++k)
            s += bf2f(Abuf[m * S + 128 + k]) * fc_W[o * HID + k];
        out[(size_t)(b0 + m) * OUTSZ + o] = sigm(s);
    }
}

extern "C" void kernel_launch(void* const* d_in, const int* in_sizes, int n_in,
                              void* d_out, int out_size, void* d_ws, size_t ws_size,
                              hipStream_t stream) {
    const float* x    = (const float*)d_in[0];
    const float* W_ih = (const float*)d_in[1];
    const float* W_hh = (const float*)d_in[2];
    const float* b_ih = (const float*)d_in[3];
    const float* b_hh = (const float*)d_in[4];
    const float* fc_W = (const float*)d_in[5];
    const float* fc_b = (const float*)d_in[6];
    float* out = (float*)d_out;

    dim3 grid(BATCH / ROWS);    // 512 blocks -> 2 per CU
    dim3 block(NTHREADS);       // 4 waves
    hipLaunchKernelGGL(lstm_fused, grid, block, 0, stream,
                       x, W_ih, W_hh, b_ih, b_hh, fc_W, fc_b, out);
}

// Round 5
// 312.566 us; speedup vs baseline: 1.2201x; 1.0744x over previous
//
#include <hip/hip_runtime.h>
#include <hip/hip_bf16.h>

#define T_STEPS 256
#define BATCH   2048
#define INSZ    65
#define HID     64
#define ROWS    4        // batch rows per block -> 512 blocks = 2 blocks/CU
#define OUTSZ   7
#define NTHREADS 256

// LDS slot bases (shorts). Frag-major layout inside each 256-short slot:
// element (row, k) at (k>>3)*32 + row*8 + (k&7).  b128 frag reads: <=2-way/bank.
#define XS0 0
#define XS1 256
#define HS0 512
#define HS1 768

typedef __attribute__((ext_vector_type(8))) short bf16x8;  // 8 bf16 = 4 VGPRs
typedef __attribute__((ext_vector_type(4))) float f32x4;

__device__ __forceinline__ short f2bf(float f) {
    union { float f; unsigned u; } v; v.f = f;
    unsigned r = (v.u + 0x7FFFu + ((v.u >> 16) & 1u)) >> 16;  // RNE
    return (short)r;
}
__device__ __forceinline__ float bf2f(short s) {
    union { unsigned u; float f; } v;
    v.u = ((unsigned)(unsigned short)s) << 16;
    return v.f;
}
__device__ __forceinline__ float sigm(float x) {
    return 1.0f / (1.0f + __expf(-x));
}
__device__ __forceinline__ float tanh_f(float x) {
    return 1.0f - 2.0f / (__expf(2.0f * x) + 1.0f);  // saturates at +-1
}
__device__ __forceinline__ float sel4(f32x4 v, int quad) {
    const float a = (quad & 1) ? v[1] : v[0];
    const float b = (quad & 1) ? v[3] : v[2];
    return (quad & 2) ? b : a;
}

__global__ __launch_bounds__(NTHREADS, 2)
void lstm_fused(const float* __restrict__ x,    const float* __restrict__ W_ih,
                const float* __restrict__ W_hh, const float* __restrict__ b_ih,
                const float* __restrict__ b_hh, const float* __restrict__ fc_W,
                const float* __restrict__ fc_b, float* __restrict__ out)
{
    __shared__ __align__(16) short Abuf[1024];

    const int tid  = threadIdx.x;
    const int w    = tid >> 6;        // wave 0..3 = hidden-col tile [16w,16w+16)
    const int lane = tid & 63;
    const int quad = lane >> 4;       // batch row this lane activates
    const int col  = lane & 15;
    const int b0   = blockIdx.x * ROWS;

    // zero h slots only (x slots are fully staged before first read)
    Abuf[HS0 + tid] = 0;
    Abuf[HS1 + tid] = 0;

    // ---- weight fragments (B layout: n = lane&15, k = quad*8+j) ----
    // kc 0,1: x-part (k 0..63 of W_ih); kc 2,3: h-part (W_hh). k=64 -> VALU fixup.
    bf16x8 wfrag[4][4];
    float  wl[4];
    f32x4  bias4[4];
    #pragma unroll
    for (int gt = 0; gt < 4; ++gt) {
        const int n = gt * 64 + w * 16 + col;
        #pragma unroll
        for (int kc = 0; kc < 2; ++kc) {
            bf16x8 f;
            #pragma unroll
            for (int j = 0; j < 8; ++j)
                f[j] = f2bf(W_ih[n * INSZ + kc * 32 + quad * 8 + j]);
            wfrag[gt][kc] = f;
        }
        #pragma unroll
        for (int kc = 2; kc < 4; ++kc) {
            bf16x8 f;
            #pragma unroll
            for (int j = 0; j < 8; ++j)
                f[j] = f2bf(W_hh[n * HID + (kc - 2) * 32 + quad * 8 + j]);
            wfrag[gt][kc] = f;
        }
        wl[gt] = W_ih[n * INSZ + 64];
        const float bv = b_ih[n] + b_hh[n];
        bias4[gt] = (f32x4){bv, bv, bv, bv};
    }

    // constant LDS offsets
    const int rbase = quad * 32 + (col & 3) * 8;               // frag read
    const int hwoff = (2 * w + (col >> 3)) * 32 + quad * 8 + (col & 7);  // h write
    const int xwoff = (lane >> 3) * 32 + w * 8 + (lane & 7);   // x stage write

    // global pointers: staging thread (w,lane) owns x[b0+w][.][lane];
    // fixup: every lane reads x[b0+quad][.][64] (16-way redundant, L1 broadcast)
    const float* xsp = x + (size_t)(b0 + w) * T_STEPS * INSZ + lane;
    const float* xep = x + (size_t)(b0 + quad) * T_STEPS * INSZ + 64;

    // stage x_0 -> XS0, x_1 -> XS1; init 4-step register pipelines
    Abuf[XS0 + xwoff] = f2bf(xsp[0]);
    Abuf[XS1 + xwoff] = f2bf(xsp[INSZ]);
    float stg[4], fix[4];                 // stg: x_{t+2..t+5}; fix: x_{t..t+3}[64]
    #pragma unroll
    for (int i = 0; i < 4; ++i) {
        stg[i] = xsp[(2 + i) * INSZ];
        fix[i] = xep[i * INSZ];
    }
    float c = 0.0f;
    f32x4 acc_x[4];
    __syncthreads();

    // acc_x(x_0) = bias + x_0 . W_ih  (pre-loop)
    {
        const bf16x8 n0 = *(const bf16x8*)&Abuf[XS0 + rbase];
        const bf16x8 n1 = *(const bf16x8*)&Abuf[XS0 + rbase + 128];
        #pragma unroll
        for (int gt = 0; gt < 4; ++gt) {
            f32x4 a = __builtin_amdgcn_mfma_f32_16x16x32_bf16(n0, wfrag[gt][0], bias4[gt], 0, 0, 0);
            acc_x[gt] = __builtin_amdgcn_mfma_f32_16x16x32_bf16(n1, wfrag[gt][1], a, 0, 0, 0);
        }
    }
    __syncthreads();    // x_0 frag reads done before body 0 overwrites XS0

    // one LSTM step. Critical path: ds_read h -> 8 MFMA -> activation -> h write.
    // acc_x for t+1 (8 MFMA) runs in the shadow of the activation VALU.
    auto STEP = [&](int XR, int XW, int HR, int HW, float xfix, float xstage) {
        const bf16x8 a2 = *(const bf16x8*)&Abuf[HR + rbase];        // h lo
        const bf16x8 a3 = *(const bf16x8*)&Abuf[HR + rbase + 128];  // h hi
        const bf16x8 n0 = *(const bf16x8*)&Abuf[XR + rbase];        // x_{t+1} lo
        const bf16x8 n1 = *(const bf16x8*)&Abuf[XR + rbase + 128];  // x_{t+1} hi
        f32x4 acc[4];
        #pragma unroll
        for (int gt = 0; gt < 4; ++gt) {
            f32x4 a = __builtin_amdgcn_mfma_f32_16x16x32_bf16(a2, wfrag[gt][2], acc_x[gt], 0, 0, 0);
            acc[gt]  = __builtin_amdgcn_mfma_f32_16x16x32_bf16(a3, wfrag[gt][3], a, 0, 0, 0);
        }
        const float gi = sigm(__builtin_fmaf(wl[0], xfix, sel4(acc[0], quad)));
        const float gf = sigm(__builtin_fmaf(wl[1], xfix, sel4(acc[1], quad)));
        const float gg = tanh_f(__builtin_fmaf(wl[2], xfix, sel4(acc[2], quad)));
        const float go = sigm(__builtin_fmaf(wl[3], xfix, sel4(acc[3], quad)));
        c = gf * c + gi * gg;
        const float h = go * tanh_f(c);
        Abuf[HW + hwoff] = f2bf(h);          // h_t
        Abuf[XW + xwoff] = f2bf(xstage);     // x_{t+2}
        #pragma unroll
        for (int gt = 0; gt < 4; ++gt) {     // acc_x for step t+1 (off critical path)
            f32x4 a = __builtin_amdgcn_mfma_f32_16x16x32_bf16(n0, wfrag[gt][0], bias4[gt], 0, 0, 0);
            acc_x[gt] = __builtin_amdgcn_mfma_f32_16x16x32_bf16(n1, wfrag[gt][1], a, 0, 0, 0);
        }
        __syncthreads();
    };

    for (int t = 0; t < T_STEPS; t += 4) {
        // all global loads for the NEXT 4-step group, issued right after a barrier:
        // 3 of the 4 barriers below then drain vmcnt with nothing outstanding.
        float ns[4], nf[4];
        #pragma unroll
        for (int i = 0; i < 4; ++i) {
            const int ts = t + 6 + i;  // stage x_{t+6+i} (clamped tail: values unused)
            const int tf = t + 4 + i;  // fixup x_{t+4+i}[64]
            ns[i] = xsp[(ts < 255 ? ts : 255) * INSZ];
            nf[i] = xep[(tf < 255 ? tf : 255) * INSZ];
        }
        STEP(XS1, XS0, HS1, HS0, fix[0], stg[0]);   // t   : read h in HS1, x_{t+1} in XS1
        STEP(XS0, XS1, HS0, HS1, fix[1], stg[1]);   // t+1
        STEP(XS1, XS0, HS1, HS0, fix[2], stg[2]);   // t+2
        STEP(XS0, XS1, HS0, HS1, fix[3], stg[3]);   // t+3
        #pragma unroll
        for (int i = 0; i < 4; ++i) { stg[i] = ns[i]; fix[i] = nf[i]; }
    }

    // ---- FC(64->7) + sigmoid; h_255 lives in HS1 (frag-major) ----
    if (tid < ROWS * OUTSZ) {
        const int m = tid & 3;
        const int o = tid >> 2;
        float s = fc_b[o];
        #pragma unroll
        for (int k = 0; k < HID; ++k)
            s += bf2f(Abuf[HS1 + (k >> 3) * 32 + m * 8 + (k & 7)]) * fc_W[o * HID + k];
        out[(size_t)(b0 + m) * OUTSZ + o] = sigm(s);
    }
}

extern "C" void kernel_launch(void* const* d_in, const int* in_sizes, int n_in,
                              void* d_out, int out_size, void* d_ws, size_t ws_size,
                              hipStream_t stream) {
    const float* x    = (const float*)d_in[0];
    const float* W_ih = (const float*)d_in[1];
    const float* W_hh = (const float*)d_in[2];
    const float* b_ih = (const float*)d_in[3];
    const float* b_hh = (const float*)d_in[4];
    const float* fc_W = (const float*)d_in[5];
    const float* fc_b = (const float*)d_in[6];
    float* out = (float*)d_out;

    dim3 grid(BATCH / ROWS);    // 512 blocks -> 2 per CU
    dim3 block(NTHREADS);       // 4 waves
    hipLaunchKernelGGL(lstm_fused, grid, block, 0, stream,
                       x, W_ih, W_hh, b_ih, b_hh, fc_W, fc_b, out);
}